// Round 7
// baseline (265.779 us; speedup 1.0000x reference)
//
#include <hip/hip_runtime.h>
#include <math.h>

// CFE hydrologic scan (R7): ILP-4.
// R6 post-mortem: LDS forcing preload regressed (global-load latency was NOT
// the stall; depth-4 register prefetch already covered it) -> reverted.
// R5 counters recalibrated: VALUBusy 17% chip-wide at 1 wave/CU means ~68%
// per-active-SIMD -> the wave is issue-dominated (~405 of 596 cyc/step), with
// ~190 cyc dependency stall. So: amortize fixed per-step overhead (forcing
// precompute, ring shift + 15-tap conv, DPP reduce, store, loop control) over
// MORE chains and let the extra chain bodies absorb the stall cycles.
//  - 4 m-chains per thread, 4 lanes per basin, 16 basins per wave
//  - 8192 threads = 128 blocks of 64 -> each wave still owns a private SIMD
//  - one ring + one conv per thread (4 chains' q summed pre-ring; conv linear)
//  - DPP reduce now 2 stages (within-quad), still pipelined 1 step behind

constexpr int T_STEPS = 730;
constexpr int BATCH   = 2048;
constexpr int NMULC   = 16;
constexpr int LENFC   = 15;
constexpr int NPHYS   = 13;
constexpr int NSTAT   = NPHYS * NMULC + 2; // 210
constexpr float NZ    = 1e-5f;
constexpr int NCH     = 4;                 // m-chains per thread
constexpr int LPB     = 4;                 // lanes per basin

__device__ __forceinline__ float frcp(float x) { return __builtin_amdgcn_rcpf(x); }

// 4-lane (quad) sum via DPP quad_perm: xor1 then xor2. All 4 lanes get the sum.
__device__ __forceinline__ float dpp_sum4(float x) {
    int v;
    v = __builtin_amdgcn_update_dpp(0, __float_as_int(x), 0xB1, 0xF, 0xF, true); // quad_perm(1,0,3,2)
    x += __int_as_float(v);
    v = __builtin_amdgcn_update_dpp(0, __float_as_int(x), 0x4E, 0xF, 0xF, true); // quad_perm(2,3,0,1)
    x += __int_as_float(v);
    return x;
}

__global__ __launch_bounds__(64, 1)
void cfe_kernel(const float* __restrict__ x,   // (T,B,2)
                const float* __restrict__ ps,  // (B,NSTAT)
                float* __restrict__ out)       // (T,B)
{
    const int tid = blockIdx.x * 64 + threadIdx.x;
    const int b   = tid >> 2;     // basin, [0,2048)
    const int m0  = tid & 3;      // handles m0, m0+4, m0+8, m0+12
    if (b >= BATCH) return;

    const float* __restrict__ row = ps + b * NSTAT;

    // ---- per-chain parameters & derived constants ----------------------
    float k1[NCH], k2[NCH], max_soil[NCH], fc_th[NCH], ic[NCH], cc[NCH],
          pc[NCH], lc[NCH], sc_c[NCH], e2[NCH], Km[NCH], Kk[NCH],
          Cgw[NCH], inv_mgw[NCH];

    #pragma unroll
    for (int c = 0; c < NCH; ++c) {
        const int m = m0 + c * 4;
        const float schaake    = row[ 0*NMULC + m] * 0.1f;
        const float smcmax     = row[ 1*NMULC + m] * 0.3f   + 0.3f;
        const float soil_depth = row[ 2*NMULC + m] * 2.5f   + 0.5f;
        const float wltsmc     = row[ 3*NMULC + m] * 0.15f  + 0.05f;
        const float satpsi     = row[ 4*NMULC + m] * 0.49f  + 0.01f;
        const float bb_        = row[ 5*NMULC + m] * 10.0f  + 2.0f;
        const float multp      = row[ 6*NMULC + m] * 1900.0f+ 100.0f;
        const float satdk      = row[ 7*NMULC + m] * (1e-4f - 1e-7f) + 1e-7f;
        const float slop       = row[ 8*NMULC + m];
        const float max_gw     = row[ 9*NMULC + m] * 0.49f  + 0.01f;
        Cgw[c]                 = row[10*NMULC + m] * (1e-3f - 1e-6f) + 1e-6f;
        const float expon      = row[11*NMULC + m] * 7.0f   + 1.0f;
        Kk[c]                  = row[12*NMULC + m] * 0.49f  + 0.01f;

        const float inv_sd  = 1.0f / soil_depth;
        const float bud_den = 1.0f / (smcmax - wltsmc + NZ);
        k1[c] = inv_sd * bud_den;
        k2[c] = -wltsmc * bud_den;
        max_soil[c] = smcmax * soil_depth;
        float fc_frac = powf(satpsi * inv_sd, 1.0f / bb_);
        fc_frac = fminf(fmaxf(fc_frac, 0.0f), 1.0f);
        fc_th[c] = smcmax * fc_frac * soil_depth;
        ic[c] = 1.0f - expf(-schaake);
        const float sm  = satdk * multp;
        const float sml = sm * slop;
        const float inv_mft = 1.0f / fmaxf(max_soil[c] - fc_th[c], NZ);
        inv_mgw[c] = 1.0f / max_gw;
        cc[c] = inv_mft * (sm + sml);
        pc[c] = sm  * inv_mft;
        lc[c] = sml * inv_mft;
        sc_c[c] = fminf(1.0f, 1.0f / cc[c]);
        e2[c] = expon * 1.442695041f;       // expon * log2(e)
        Km[c] = 1.0f - Kk[c];
    }
    const float inv_nz = 1.0f / NZ;

    // ---- routing weights: per-basin, shared by all 4 chains ------------
    const float rout_a = row[NPHYS*NMULC + 0] * 2.9f;
    const float rout_b = row[NPHYS*NMULC + 1] * 6.5f;
    const float a  = fmaxf(rout_a, 0.0f) + 0.1f;
    const float th = fmaxf(rout_b, 0.0f) + 0.5f;
    float w[LENFC];
    float wsum = 0.0f;
    #pragma unroll
    for (int j = 0; j < LENFC; ++j) {
        const float tj = (float)j + 0.5f;
        w[j] = powf(tj, a - 1.0f) * expf(-tj / th);
        wsum += w[j];
    }
    const float wscale = 1.0f / (wsum * (float)NMULC);
    #pragma unroll
    for (int j = 0; j < LENFC; ++j) w[j] *= wscale;

    // ---- state ----------------------------------------------------------
    float soil[NCH], gw[NCH], n0[NCH], n1[NCH], n2[NCH];
    #pragma unroll
    for (int c = 0; c < NCH; ++c) {
        soil[c] = 0.05f; gw[c] = 0.01f; n0[c] = NZ; n1[c] = NZ; n2[c] = NZ;
    }
    float ring[LENFC];
    #pragma unroll
    for (int j = 0; j < LENFC; ++j) ring[j] = 0.0f;

    const float2* __restrict__ xp = (const float2*)x;

    // ---- forcing prefetch ring, depth 4 (global; R6 showed LDS staging
    // is NOT better -- depth-4 register prefetch covers the latency) ------
    float2 fb0 = xp[0 * BATCH + b];
    float2 fb1 = xp[1 * BATCH + b];
    float2 fb2 = xp[2 * BATCH + b];
    float2 fb3 = xp[3 * BATCH + b];

    float s_prev = 0.0f;

    #pragma unroll 2
    for (int t = 0; t < T_STEPS; ++t) {
        // ---- pipelined DPP4 reduction + store for step t-1 (off-chain) --
        {
            const float r = dpp_sum4(s_prev);
            if (t > 0 && m0 == 0) out[(t - 1) * BATCH + b] = r;
        }

        const float p   = fb0.x;
        const float pet = fb0.y;
        fb0 = fb1; fb1 = fb2; fb2 = fb3;
        const int tn = (t + 4 < T_STEPS) ? (t + 4) : (T_STEPS - 1);
        fb3 = xp[tn * BATCH + b];

        // -- shared forcing precompute
        const float et_rain = fminf(p, pet);
        const float p_rem   = p - et_rain;
        const float pet_rem = pet - et_rain;
        const float prem_nz = p_rem + NZ;
        const float prem_sq = p_rem * p_rem;

        // -- four independent chain bodies (compiler interleaves them)
        float qsum = 0.0f;
        #pragma unroll
        for (int c = 0; c < NCH; ++c) {
            float budyko = fmaf(soil[c], k1[c], k2[c]);
            budyko = fminf(fmaxf(budyko, 0.0f), 1.0f);
            const float aet = fminf(pet_rem * budyko, soil[c] - NZ);
            float so = soil[c] - aet;

            const float deficit = max_soil[c] - so;
            const float den     = fmaf(deficit, ic[c], prem_nz);
            const float runoff0 = prem_sq * frcp(den);
            const float infil   = fminf(p_rem - runoff0, deficit);
            const float runoff  = p_rem - infil;
            so += infil;

            const float above = fmaxf(so - fc_th[c], 0.0f);
            const float asc   = fminf(above * sc_c[c], above * above * inv_nz);
            const float lat   = lc[c] * asc;
            so = fmaf(-cc[c], asc, so);
            soil[c] = so;

            float g = fmaf(pc[c], asc, gw[c]);
            const float ratio = fminf(g * inv_mgw[c], 1.0f);
            const float qg0   = fmaf(Cgw[c], __builtin_amdgcn_exp2f(e2[c] * ratio), -Cgw[c]);
            const float qg    = fminf(qg0, g - NZ);
            gw[c] = g - qg;

            const float s0 = n0[c] + lat;            const float s1 = fmaf(Kk[c], s0, n1[c]);
            const float s2 = fmaf(Kk[c], s1, n2[c]); const float o2 = Kk[c] * s2;
            n0[c] = Km[c] * s0; n1[c] = Km[c] * s1; n2[c] = Km[c] * s2;

            qsum += runoff + o2 + qg;
        }

        // -- one ring + one 15-tap conv per thread (conv linear in q)
        #pragma unroll
        for (int j = LENFC - 1; j > 0; --j) ring[j] = ring[j - 1];
        ring[0] = qsum;
        float c0 = 0.0f, c1 = 0.0f, c2 = 0.0f, c3 = 0.0f;
        #pragma unroll
        for (int j = 0; j < LENFC; j += 4) {
            c0 = fmaf(w[j], ring[j], c0);
            if (j + 1 < LENFC) c1 = fmaf(w[j + 1], ring[j + 1], c1);
            if (j + 2 < LENFC) c2 = fmaf(w[j + 2], ring[j + 2], c2);
            if (j + 3 < LENFC) c3 = fmaf(w[j + 3], ring[j + 3], c3);
        }
        s_prev = (c0 + c1) + (c2 + c3);
    }

    // ---- epilogue --------------------------------------------------------
    {
        const float r = dpp_sum4(s_prev);
        if (m0 == 0) out[(T_STEPS - 1) * BATCH + b] = r;
    }
}

extern "C" void kernel_launch(void* const* d_in, const int* in_sizes, int n_in,
                              void* d_out, int out_size, void* d_ws, size_t ws_size,
                              hipStream_t stream) {
    const float* x_phy      = (const float*)d_in[0];
    const float* phy_static = (const float*)d_in[1];
    float* out = (float*)d_out;

    const int total = BATCH * LPB;              // 8192 threads
    const int block = 64;
    const int grid  = total / block;            // 128 blocks
    cfe_kernel<<<grid, block, 0, stream>>>(x_phy, phy_static, out);
}

// Round 8
// 177.402 us; speedup vs baseline: 1.4982x; 1.4982x over previous
//
#include <hip/hip_runtime.h>
#include <math.h>

// CFE hydrologic scan (R8): compile-time ring rotation.
// Config: R5's proven Pareto point (NCH=2 chains/thread, 8 lanes/basin,
// 256 waves = 1 wave/CU). R7 (NCH=4, 128 waves) regressed: per-wave
// efficiency rose but half the CUs idled -- wave count x ILP is fixed.
// R8 attacks the ~120 instr/step fixed overhead seen in R5:
//  - time loop unrolled in blocks of 15 (= conv length): slot = t%15 is
//    compile-time, so ring[slot] and all conv taps are static indices ->
//    ring lives in registers with ZERO shift movs (was 15 movs/step)
//  - forcing loads batched 15/block at block top (addresses known; latency
//    covered by the previous block's ~1000+ cyc of compute)
//  - depth-4 prefetch rotation movs gone (6/step)
//  - reduce+store inlined per step: off the recurrence, costs issue only
// Math stream is IDENTICAL to R5 (same ops, same order) -> absmax unchanged.

constexpr int T_STEPS = 730;
constexpr int BATCH   = 2048;
constexpr int NMULC   = 16;
constexpr int LENFC   = 15;
constexpr int NPHYS   = 13;
constexpr int NSTAT   = NPHYS * NMULC + 2; // 210
constexpr float NZ    = 1e-5f;
constexpr float INV_NZ= 1e5f;
constexpr int NCH     = 2;                 // m-chains per thread
constexpr int LPB     = 8;                 // lanes per basin
constexpr int TB      = 15;                // steps per unrolled block
constexpr int T_MAIN  = 720;               // 48 * 15; tail = 10

__device__ __forceinline__ float frcp(float x) { return __builtin_amdgcn_rcpf(x); }

// 8-lane group sum via DPP (quad_perm xor1, xor2, row_half_mirror).
__device__ __forceinline__ float dpp_sum8(float x) {
    int v;
    v = __builtin_amdgcn_update_dpp(0, __float_as_int(x), 0xB1, 0xF, 0xF, true);  // quad_perm(1,0,3,2)
    x += __int_as_float(v);
    v = __builtin_amdgcn_update_dpp(0, __float_as_int(x), 0x4E, 0xF, 0xF, true);  // quad_perm(2,3,0,1)
    x += __int_as_float(v);
    v = __builtin_amdgcn_update_dpp(0, __float_as_int(x), 0x141, 0xF, 0xF, true); // row_half_mirror
    x += __int_as_float(v);
    return x;
}

struct Prm {
    float k1[NCH], k2[NCH], ms[NCH], fc[NCH], ic[NCH], cc[NCH], pc[NCH],
          lc[NCH], sc[NCH], e2[NCH], Km[NCH], Kk[NCH], Cg[NCH], ig[NCH];
    float w[LENFC];
};
struct St { float soil[NCH], gw[NCH], n0[NCH], n1[NCH], n2[NCH]; };

// One timestep; SLOT = t % 15 (compile-time). Writes ring[SLOT], returns the
// lane-local 15-tap conv output (pre-reduction). All ring indices static.
template <int SLOT>
__device__ __forceinline__ float substep(const Prm& P, St& S,
                                         float (&ring)[LENFC], const float2 fv)
{
    const float p = fv.x, pet = fv.y;
    const float et      = fminf(p, pet);
    const float p_rem   = p - et;
    const float pet_rem = pet - et;
    const float prem_nz = p_rem + NZ;
    const float prem_sq = p_rem * p_rem;

    float qsum = 0.0f;
    #pragma unroll
    for (int c = 0; c < NCH; ++c) {
        float budyko = fmaf(S.soil[c], P.k1[c], P.k2[c]);
        budyko = fminf(fmaxf(budyko, 0.0f), 1.0f);
        const float aet = fminf(pet_rem * budyko, S.soil[c] - NZ);
        float so = S.soil[c] - aet;

        const float deficit = P.ms[c] - so;
        const float den     = fmaf(deficit, P.ic[c], prem_nz);
        const float runoff0 = prem_sq * frcp(den);
        const float infil   = fminf(p_rem - runoff0, deficit);
        const float runoff  = p_rem - infil;
        so += infil;

        const float above = fmaxf(so - P.fc[c], 0.0f);
        const float asc   = fminf(above * P.sc[c], above * above * INV_NZ);
        const float lat   = P.lc[c] * asc;
        so = fmaf(-P.cc[c], asc, so);
        S.soil[c] = so;

        float g = fmaf(P.pc[c], asc, S.gw[c]);
        const float ratio = fminf(g * P.ig[c], 1.0f);
        const float qg0   = fmaf(P.Cg[c], __builtin_amdgcn_exp2f(P.e2[c] * ratio), -P.Cg[c]);
        const float qg    = fminf(qg0, g - NZ);
        S.gw[c] = g - qg;

        const float s0 = S.n0[c] + lat;             const float s1 = fmaf(P.Kk[c], s0, S.n1[c]);
        const float s2 = fmaf(P.Kk[c], s1, S.n2[c]); const float o2 = P.Kk[c] * s2;
        S.n0[c] = P.Km[c] * s0; S.n1[c] = P.Km[c] * s1; S.n2[c] = P.Km[c] * s2;

        qsum += runoff + o2 + qg;
    }

    ring[SLOT] = qsum;
    float c0 = 0.0f, c1 = 0.0f, c2 = 0.0f, c3 = 0.0f;
    #pragma unroll
    for (int j = 0; j < LENFC; j += 4) {
        c0 = fmaf(P.w[j], ring[(SLOT - j + 15) % 15], c0);
        if (j + 1 < LENFC) c1 = fmaf(P.w[j + 1], ring[(SLOT - j - 1 + 30) % 15], c1);
        if (j + 2 < LENFC) c2 = fmaf(P.w[j + 2], ring[(SLOT - j - 2 + 30) % 15], c2);
        if (j + 3 < LENFC) c3 = fmaf(P.w[j + 3], ring[(SLOT - j - 3 + 30) % 15], c3);
    }
    return (c0 + c1) + (c2 + c3);
}

#define SUBST(s) { const float acc = substep<(s)>(P, S, ring, f[(s)]);           \
                   const float r = dpp_sum8(acc);                                \
                   if (lane0) out[(tb + (s)) * BATCH + b] = r; }
#define DO15(X) X(0) X(1) X(2) X(3) X(4) X(5) X(6) X(7) X(8) X(9) X(10) X(11) X(12) X(13) X(14)
#define DO10(X) X(0) X(1) X(2) X(3) X(4) X(5) X(6) X(7) X(8) X(9)

__global__ __launch_bounds__(64, 1)
void cfe_kernel(const float* __restrict__ x,   // (T,B,2)
                const float* __restrict__ ps,  // (B,NSTAT)
                float* __restrict__ out)       // (T,B)
{
    const int tid = blockIdx.x * 64 + threadIdx.x;
    const int b   = tid >> 3;     // basin
    const int m0  = tid & 7;      // handles m0 and m0+8
    const bool lane0 = (m0 == 0);

    const float* __restrict__ row = ps + b * NSTAT;

    Prm P;
    #pragma unroll
    for (int c = 0; c < NCH; ++c) {
        const int m = m0 + c * 8;
        const float schaake    = row[ 0*NMULC + m] * 0.1f;
        const float smcmax     = row[ 1*NMULC + m] * 0.3f   + 0.3f;
        const float soil_depth = row[ 2*NMULC + m] * 2.5f   + 0.5f;
        const float wltsmc     = row[ 3*NMULC + m] * 0.15f  + 0.05f;
        const float satpsi     = row[ 4*NMULC + m] * 0.49f  + 0.01f;
        const float bb_        = row[ 5*NMULC + m] * 10.0f  + 2.0f;
        const float multp      = row[ 6*NMULC + m] * 1900.0f+ 100.0f;
        const float satdk      = row[ 7*NMULC + m] * (1e-4f - 1e-7f) + 1e-7f;
        const float slop       = row[ 8*NMULC + m];
        const float max_gw     = row[ 9*NMULC + m] * 0.49f  + 0.01f;
        P.Cg[c]                = row[10*NMULC + m] * (1e-3f - 1e-6f) + 1e-6f;
        const float expon      = row[11*NMULC + m] * 7.0f   + 1.0f;
        P.Kk[c]                = row[12*NMULC + m] * 0.49f  + 0.01f;

        const float inv_sd  = 1.0f / soil_depth;
        const float bud_den = 1.0f / (smcmax - wltsmc + NZ);
        P.k1[c] = inv_sd * bud_den;
        P.k2[c] = -wltsmc * bud_den;
        P.ms[c] = smcmax * soil_depth;
        float fc_frac = powf(satpsi * inv_sd, 1.0f / bb_);
        fc_frac = fminf(fmaxf(fc_frac, 0.0f), 1.0f);
        P.fc[c] = smcmax * fc_frac * soil_depth;
        P.ic[c] = 1.0f - expf(-schaake);
        const float sm  = satdk * multp;
        const float sml = sm * slop;
        const float inv_mft = 1.0f / fmaxf(P.ms[c] - P.fc[c], NZ);
        P.ig[c] = 1.0f / max_gw;
        P.cc[c] = inv_mft * (sm + sml);
        P.pc[c] = sm  * inv_mft;
        P.lc[c] = sml * inv_mft;
        P.sc[c] = fminf(1.0f, 1.0f / P.cc[c]);
        P.e2[c] = expon * 1.442695041f;     // expon * log2(e)
        P.Km[c] = 1.0f - P.Kk[c];
    }

    // routing weights: per-basin, shared by both chains
    {
        const float rout_a = row[NPHYS*NMULC + 0] * 2.9f;
        const float rout_b = row[NPHYS*NMULC + 1] * 6.5f;
        const float a  = fmaxf(rout_a, 0.0f) + 0.1f;
        const float th = fmaxf(rout_b, 0.0f) + 0.5f;
        float wsum = 0.0f;
        #pragma unroll
        for (int j = 0; j < LENFC; ++j) {
            const float tj = (float)j + 0.5f;
            P.w[j] = powf(tj, a - 1.0f) * expf(-tj / th);
            wsum += P.w[j];
        }
        const float wscale = 1.0f / (wsum * (float)NMULC);
        #pragma unroll
        for (int j = 0; j < LENFC; ++j) P.w[j] *= wscale;
    }

    St S;
    #pragma unroll
    for (int c = 0; c < NCH; ++c) {
        S.soil[c] = 0.05f; S.gw[c] = 0.01f;
        S.n0[c] = NZ; S.n1[c] = NZ; S.n2[c] = NZ;
    }
    float ring[LENFC];
    #pragma unroll
    for (int j = 0; j < LENFC; ++j) ring[j] = 0.0f;

    const float2* __restrict__ xp = (const float2*)x;

    // ---- main loop: 48 blocks of 15 steps; slot = t%15 is compile-time --
    #pragma unroll 1
    for (int tb = 0; tb < T_MAIN; tb += TB) {
        float2 f[TB];
        #pragma unroll
        for (int s = 0; s < TB; ++s) f[s] = xp[(tb + s) * BATCH + b];
        DO15(SUBST)
    }

    // ---- tail: 10 steps (720..729); 720 % 15 == 0 so slots 0..9 ---------
    {
        const int tb = T_MAIN;
        float2 f[10];
        #pragma unroll
        for (int s = 0; s < 10; ++s) f[s] = xp[(tb + s) * BATCH + b];
        DO10(SUBST)
    }
}

extern "C" void kernel_launch(void* const* d_in, const int* in_sizes, int n_in,
                              void* d_out, int out_size, void* d_ws, size_t ws_size,
                              hipStream_t stream) {
    const float* x_phy      = (const float*)d_in[0];
    const float* phy_static = (const float*)d_in[1];
    float* out = (float*)d_out;

    const int total = BATCH * LPB;              // 16384 threads
    const int block = 64;
    const int grid  = total / block;            // 256 blocks -> 1 per CU
    cfe_kernel<<<grid, block, 0, stream>>>(x_phy, phy_static, out);
}

// Round 9
// 155.996 us; speedup vs baseline: 1.7038x; 1.1372x over previous
//
#include <hip/hip_runtime.h>
#include <math.h>

// CFE hydrologic scan (R9): packed-FP32 chains + double-buffered forcing.
// Config: R5/R8 Pareto point (NCH=2 chains/thread, 8 lanes/basin, 256 waves,
// 1 wave/CU). R8 post-mortem: static ring saved little; issue stream is the
// binding term (~400 of 582 cyc/step) plus ~180 cyc stall.
// R9:
//  (1) chain math on float2 ext-vectors -> v_pk_fma_f32/v_pk_mul_f32/
//      v_pk_add_f32 (CDNA packed FP32): both chains in one instruction for
//      every packable op; min/max/rcp/exp2 scalarize. Same per-element ops,
//      same order -> bitwise-identical results.
//  (2) forcing loads double-buffered: block k's compute covers block k+1's
//      15 loads (removes the periodic first-use latency edge R8 had).

constexpr int T_STEPS = 730;
constexpr int BATCH   = 2048;
constexpr int NMULC   = 16;
constexpr int LENFC   = 15;
constexpr int NPHYS   = 13;
constexpr int NSTAT   = NPHYS * NMULC + 2; // 210
constexpr float NZ    = 1e-5f;
constexpr float INV_NZ= 1e5f;
constexpr int NCH     = 2;                 // m-chains per thread (packed)
constexpr int LPB     = 8;                 // lanes per basin
constexpr int TB      = 15;                // steps per unrolled block
constexpr int T_MAIN  = 720;               // 24 x 30; tail = 10

typedef float v2f __attribute__((ext_vector_type(2)));

__device__ __forceinline__ float frcp(float x) { return __builtin_amdgcn_rcpf(x); }
__device__ __forceinline__ v2f v2(float s) { return (v2f){s, s}; }
__device__ __forceinline__ v2f vmin(v2f a, v2f b) { return __builtin_elementwise_min(a, b); }
__device__ __forceinline__ v2f vmax(v2f a, v2f b) { return __builtin_elementwise_max(a, b); }

// 8-lane group sum via DPP (quad_perm xor1, xor2, row_half_mirror).
__device__ __forceinline__ float dpp_sum8(float x) {
    int v;
    v = __builtin_amdgcn_update_dpp(0, __float_as_int(x), 0xB1, 0xF, 0xF, true);  // quad_perm(1,0,3,2)
    x += __int_as_float(v);
    v = __builtin_amdgcn_update_dpp(0, __float_as_int(x), 0x4E, 0xF, 0xF, true);  // quad_perm(2,3,0,1)
    x += __int_as_float(v);
    v = __builtin_amdgcn_update_dpp(0, __float_as_int(x), 0x141, 0xF, 0xF, true); // row_half_mirror
    x += __int_as_float(v);
    return x;
}

struct Prm {
    v2f k1, k2, ms, fc, ic, cc, pc, lc, sc, e2, Km, Kk, Cg, ig;
    float w[LENFC];
};
struct St { v2f soil, gw, n0, n1, n2; };

// One timestep; SLOT = t % 15 (compile-time -> static ring indices).
template <int SLOT>
__device__ __forceinline__ float substep(const Prm& P, St& S,
                                         float (&ring)[LENFC], const float2 fv)
{
    const float p = fv.x, pet = fv.y;
    const float et      = fminf(p, pet);
    const float p_rem   = p - et;
    const float pet_rem = pet - et;
    const float prem_nz = p_rem + NZ;
    const float prem_sq = p_rem * p_rem;

    // -- both chains as one packed stream --------------------------------
    v2f budyko = S.soil * P.k1 + P.k2;                       // pk_fma
    budyko = vmin(vmax(budyko, v2(0.0f)), v2(1.0f));
    const v2f aet = vmin(v2(pet_rem) * budyko, S.soil - v2(NZ));
    v2f so = S.soil - aet;

    const v2f deficit = P.ms - so;
    const v2f den     = deficit * P.ic + v2(prem_nz);        // pk_fma
    v2f rden; rden.x = frcp(den.x); rden.y = frcp(den.y);
    const v2f runoff0 = v2(prem_sq) * rden;
    const v2f infil   = vmin(v2(p_rem) - runoff0, deficit);
    const v2f runoff  = v2(p_rem) - infil;
    so += infil;

    const v2f above = vmax(so - P.fc, v2(0.0f));
    const v2f asc   = vmin(above * P.sc, above * above * v2(INV_NZ));
    const v2f lat   = P.lc * asc;
    so = so - P.cc * asc;                                    // pk_fma (neg)
    S.soil = so;

    v2f g = P.pc * asc + S.gw;                               // pk_fma
    const v2f ratio = vmin(g * P.ig, v2(1.0f));
    v2f ex;
    ex.x = __builtin_amdgcn_exp2f(P.e2.x * ratio.x);
    ex.y = __builtin_amdgcn_exp2f(P.e2.y * ratio.y);
    const v2f qg0 = P.Cg * ex - P.Cg;                        // pk_fma
    const v2f qg  = vmin(qg0, g - v2(NZ));
    S.gw = g - qg;

    const v2f s0 = S.n0 + lat;
    const v2f s1 = P.Kk * s0 + S.n1;                         // pk_fma
    const v2f s2 = P.Kk * s1 + S.n2;                         // pk_fma
    const v2f o2 = P.Kk * s2;
    S.n0 = P.Km * s0; S.n1 = P.Km * s1; S.n2 = P.Km * s2;

    const v2f qv = runoff + o2 + qg;
    const float qsum = qv.x + qv.y;

    ring[SLOT] = qsum;
    float c0 = 0.0f, c1 = 0.0f, c2 = 0.0f, c3 = 0.0f;
    #pragma unroll
    for (int j = 0; j < LENFC; j += 4) {
        c0 = fmaf(P.w[j], ring[(SLOT - j + 15) % 15], c0);
        if (j + 1 < LENFC) c1 = fmaf(P.w[j + 1], ring[(SLOT - j - 1 + 30) % 15], c1);
        if (j + 2 < LENFC) c2 = fmaf(P.w[j + 2], ring[(SLOT - j - 2 + 30) % 15], c2);
        if (j + 3 < LENFC) c3 = fmaf(P.w[j + 3], ring[(SLOT - j - 3 + 30) % 15], c3);
    }
    return (c0 + c1) + (c2 + c3);
}

#define SUBST(s, FBUF, TBASE) {                                              \
    const float acc = substep<(s)>(P, S, ring, FBUF[(s)]);                   \
    const float r = dpp_sum8(acc);                                           \
    if (lane0) out[((TBASE) + (s)) * BATCH + b] = r; }
#define DO15(FBUF, TBASE) \
    SUBST(0,FBUF,TBASE) SUBST(1,FBUF,TBASE) SUBST(2,FBUF,TBASE)  \
    SUBST(3,FBUF,TBASE) SUBST(4,FBUF,TBASE) SUBST(5,FBUF,TBASE)  \
    SUBST(6,FBUF,TBASE) SUBST(7,FBUF,TBASE) SUBST(8,FBUF,TBASE)  \
    SUBST(9,FBUF,TBASE) SUBST(10,FBUF,TBASE) SUBST(11,FBUF,TBASE)\
    SUBST(12,FBUF,TBASE) SUBST(13,FBUF,TBASE) SUBST(14,FBUF,TBASE)
#define DO10(FBUF, TBASE) \
    SUBST(0,FBUF,TBASE) SUBST(1,FBUF,TBASE) SUBST(2,FBUF,TBASE)  \
    SUBST(3,FBUF,TBASE) SUBST(4,FBUF,TBASE) SUBST(5,FBUF,TBASE)  \
    SUBST(6,FBUF,TBASE) SUBST(7,FBUF,TBASE) SUBST(8,FBUF,TBASE)  \
    SUBST(9,FBUF,TBASE)

__global__ __launch_bounds__(64, 1)
void cfe_kernel(const float* __restrict__ x,   // (T,B,2)
                const float* __restrict__ ps,  // (B,NSTAT)
                float* __restrict__ out)       // (T,B)
{
    const int tid = blockIdx.x * 64 + threadIdx.x;
    const int b   = tid >> 3;     // basin
    const int m0  = tid & 7;      // handles m0 and m0+8
    const bool lane0 = (m0 == 0);

    const float* __restrict__ row = ps + b * NSTAT;

    Prm P;
    #pragma unroll
    for (int c = 0; c < NCH; ++c) {
        const int m = m0 + c * 8;
        const float schaake    = row[ 0*NMULC + m] * 0.1f;
        const float smcmax     = row[ 1*NMULC + m] * 0.3f   + 0.3f;
        const float soil_depth = row[ 2*NMULC + m] * 2.5f   + 0.5f;
        const float wltsmc     = row[ 3*NMULC + m] * 0.15f  + 0.05f;
        const float satpsi     = row[ 4*NMULC + m] * 0.49f  + 0.01f;
        const float bb_        = row[ 5*NMULC + m] * 10.0f  + 2.0f;
        const float multp      = row[ 6*NMULC + m] * 1900.0f+ 100.0f;
        const float satdk      = row[ 7*NMULC + m] * (1e-4f - 1e-7f) + 1e-7f;
        const float slop       = row[ 8*NMULC + m];
        const float max_gw     = row[ 9*NMULC + m] * 0.49f  + 0.01f;
        const float Cgw        = row[10*NMULC + m] * (1e-3f - 1e-6f) + 1e-6f;
        const float expon      = row[11*NMULC + m] * 7.0f   + 1.0f;
        const float K          = row[12*NMULC + m] * 0.49f  + 0.01f;

        const float inv_sd  = 1.0f / soil_depth;
        const float bud_den = 1.0f / (smcmax - wltsmc + NZ);
        const float ms      = smcmax * soil_depth;
        float fc_frac = powf(satpsi * inv_sd, 1.0f / bb_);
        fc_frac = fminf(fmaxf(fc_frac, 0.0f), 1.0f);
        const float fc      = smcmax * fc_frac * soil_depth;
        const float sm      = satdk * multp;
        const float sml     = sm * slop;
        const float inv_mft = 1.0f / fmaxf(ms - fc, NZ);
        const float ccv     = inv_mft * (sm + sml);

        P.k1[c] = inv_sd * bud_den;
        P.k2[c] = -wltsmc * bud_den;
        P.ms[c] = ms;
        P.fc[c] = fc;
        P.ic[c] = 1.0f - expf(-schaake);
        P.cc[c] = ccv;
        P.pc[c] = sm  * inv_mft;
        P.lc[c] = sml * inv_mft;
        P.sc[c] = fminf(1.0f, 1.0f / ccv);
        P.e2[c] = expon * 1.442695041f;     // expon * log2(e)
        P.Km[c] = 1.0f - K;
        P.Kk[c] = K;
        P.Cg[c] = Cgw;
        P.ig[c] = 1.0f / max_gw;
    }

    // routing weights: per-basin, shared by both chains
    {
        const float rout_a = row[NPHYS*NMULC + 0] * 2.9f;
        const float rout_b = row[NPHYS*NMULC + 1] * 6.5f;
        const float a  = fmaxf(rout_a, 0.0f) + 0.1f;
        const float th = fmaxf(rout_b, 0.0f) + 0.5f;
        float wsum = 0.0f;
        #pragma unroll
        for (int j = 0; j < LENFC; ++j) {
            const float tj = (float)j + 0.5f;
            P.w[j] = powf(tj, a - 1.0f) * expf(-tj / th);
            wsum += P.w[j];
        }
        const float wscale = 1.0f / (wsum * (float)NMULC);
        #pragma unroll
        for (int j = 0; j < LENFC; ++j) P.w[j] *= wscale;
    }

    St S;
    S.soil = v2(0.05f); S.gw = v2(0.01f);
    S.n0 = v2(NZ); S.n1 = v2(NZ); S.n2 = v2(NZ);
    float ring[LENFC];
    #pragma unroll
    for (int j = 0; j < LENFC; ++j) ring[j] = 0.0f;

    const float2* __restrict__ xp = (const float2*)x;

    // ---- forcing double-buffer: fA holds current block, fB prefetched ---
    float2 fA[TB], fB[TB];
    #pragma unroll
    for (int s = 0; s < TB; ++s) fA[s] = xp[s * BATCH + b];

    #pragma unroll 1
    for (int tb = 0; tb < T_MAIN; tb += 2 * TB) {
        // prefetch next block (tb+15) while computing on fA
        #pragma unroll
        for (int s = 0; s < TB; ++s) {
            int t = tb + TB + s; if (t > T_STEPS - 1) t = T_STEPS - 1;
            fB[s] = xp[t * BATCH + b];
        }
        DO15(fA, tb)
        // prefetch block tb+30 while computing on fB
        #pragma unroll
        for (int s = 0; s < TB; ++s) {
            int t = tb + 2 * TB + s; if (t > T_STEPS - 1) t = T_STEPS - 1;
            fA[s] = xp[t * BATCH + b];
        }
        DO15(fB, tb + TB)
    }

    // ---- tail: 10 steps (720..729); fA already holds them (clamped load)
    DO10(fA, T_MAIN)
}

extern "C" void kernel_launch(void* const* d_in, const int* in_sizes, int n_in,
                              void* d_out, int out_size, void* d_ws, size_t ws_size,
                              hipStream_t stream) {
    const float* x_phy      = (const float*)d_in[0];
    const float* phy_static = (const float*)d_in[1];
    float* out = (float*)d_out;

    const int total = BATCH * LPB;              // 16384 threads
    const int block = 64;
    const int grid  = total / block;            // 256 blocks -> 1 per CU
    cfe_kernel<<<grid, block, 0, stream>>>(x_phy, phy_static, out);
}